// Round 10
// baseline (1690.292 us; speedup 1.0000x reference)
//
#include <hip/hip_runtime.h>

#define N_PTS 8192
#define R2F 0.015625f   // R*R, exactly representable

// Phase-disjoint LDS regions share one union:
//  s  : per-wave sorted top-64 lists (extraction -> merge)   [R8-verbatim path]
//  p2 : W1s (W1a only) + transposed x-gather   (phase 2)
//  p3 : W2s + aggS                             (phase 3/4)
union Big {
    struct { unsigned mb[4][64]; unsigned mj[4][64]; } s;   // 2 KB
    struct { float W1s[64][64]; float xsT[64][68]; } p2;    // 33792 B
    struct { float W2s[64][128]; float aggS[128]; } p3;     // 33280 B
};

__global__ __launch_bounds__(256) void fused_all(const float* __restrict__ x,
                                                 const float* __restrict__ pos,
                                                 const float* __restrict__ W1,
                                                 const float* __restrict__ b1,
                                                 const float* __restrict__ W2,
                                                 const float* __restrict__ b2,
                                                 const float* __restrict__ Wg,
                                                 const float* __restrict__ bg,
                                                 float* __restrict__ out) {
    __shared__ Big   u0;
    __shared__ float h1T[64][68];    // transposed h1 (pad 68: conflict-free)
    __shared__ float pmw[4][128];    // per-wave partial maxima
    __shared__ unsigned selb[64];
    __shared__ int   selj[64];
    __shared__ int   nvalidS;

    const int t    = threadIdx.x;
    const int lane = t & 63;
    const int w    = t >> 6;         // wave id; owns quarter j in [2048w, 2048w+2048)
    const int qb   = w << 11;
    const int i    = blockIdx.x;

    const float xi = pos[i * 3 + 0], yi = pos[i * 3 + 1], zi = pos[i * 3 + 2];
    const float sqi = __fadd_rn(__fadd_rn(__fmul_rn(xi, xi), __fmul_rn(yi, yi)),
                                __fmul_rn(zi, zi));

    // ================= extraction: R8-VERBATIM (proven bit-exact) ==========
    unsigned kb[32];
    #pragma unroll
    for (int k = 0; k < 32; ++k) {
        const int j = qb + lane + (k << 6);
        const float xj = pos[j * 3 + 0], yj = pos[j * 3 + 1], zj = pos[j * 3 + 2];
        const float sqj = __fadd_rn(__fadd_rn(__fmul_rn(xj, xj), __fmul_rn(yj, yj)),
                                    __fmul_rn(zj, zj));
        const float dot = __fmaf_rn(zi, zj, __fmaf_rn(yi, yj, __fmul_rn(xi, xj)));
        const float d2  = __fsub_rn(__fadd_rn(sqi, sqj), __fmul_rn(2.0f, dot));
        unsigned b = __float_as_uint(d2);
        kb[k] = (b & 0x80000000u) ? ~b : (b | 0x80000000u);  // monotone total order
    }

    unsigned removed = 0u;
    for (int s = 0; s < 64; ++s) {
        unsigned lb = 0xFFFFFFFFu;
        int      lj = 0x7FFFFFFF;
        #pragma unroll
        for (int k = 0; k < 32; ++k) {
            if (!(removed & (1u << k))) {
                const unsigned b = kb[k];
                if (b < lb) { lb = b; lj = qb + lane + (k << 6); }
            }
        }
        unsigned rb = lb;
        int      rj = lj;
        #pragma unroll
        for (int off = 32; off > 0; off >>= 1) {
            const unsigned ob = (unsigned)__shfl_down((int)rb, off);
            const int      oj = __shfl_down(rj, off);
            if (ob < rb || (ob == rb && oj < rj)) { rb = ob; rj = oj; }
        }
        const unsigned wb = (unsigned)__shfl((int)rb, 0);
        const int      wj = __shfl(rj, 0);
        if (lane == 0) { u0.s.mb[w][s] = wb; u0.s.mj[w][s] = (unsigned)wj; }
        if (lb == wb && lj == wj)                         // unique owner lane
            removed |= 1u << ((wj - qb - lane) >> 6);
    }
    __syncthreads();

    {   // merge: exact global top-64 by (b, j) via parallel rank (R8-verbatim)
        const int p = lane;
        const unsigned be = u0.s.mb[w][p];
        const unsigned je = u0.s.mj[w][p];
        int rank = p;
        #pragma unroll
        for (int d = 1; d < 4; ++d) {
            const int wp = (w + d) & 3;
            int lo = 0;
            #pragma unroll
            for (int st = 32; st > 0; st >>= 1) {
                const int idx = lo + st - 1;
                const unsigned ob = u0.s.mb[wp][idx];
                const unsigned oj = u0.s.mj[wp][idx];
                if (ob < be || (ob == be && oj < je)) lo += st;
            }
            {
                const unsigned ob = u0.s.mb[wp][lo];
                const unsigned oj = u0.s.mj[wp][lo];
                if (ob < be || (ob == be && oj < je)) lo += 1;
            }
            rank += lo;
        }
        if (rank < 64) { selb[rank] = be; selj[rank] = (int)je; }
    }
    __syncthreads();

    // ======== stage W1a + transposed x-gather + nvalid ballot ==============
    {
        const float4* src = (const float4*)W1;
        float4*       dst = (float4*)&u0.p2.W1s[0][0];
        for (int v = t; v < 1024; v += 256) dst[v] = src[v];   // rows 0..63
    }
    for (int v = t; v < 1024; v += 256) {
        const int n = v >> 4, c4 = (v & 15) * 4;   // rows >= nvalid never used
        const float4 g = *(const float4*)&x[selj[n] * 64 + c4];
        u0.p2.xsT[c4 + 0][n] = g.x;
        u0.p2.xsT[c4 + 1][n] = g.y;
        u0.p2.xsT[c4 + 2][n] = g.z;
        u0.p2.xsT[c4 + 3][n] = g.w;
    }
    {
        bool ok = false;
        if (t < 64) {
            const unsigned b = selb[t];
            const unsigned db = (b & 0x80000000u) ? (b ^ 0x80000000u) : ~b;
            ok = (__uint_as_float(db) <= R2F);
        }
        const unsigned long long vm = __ballot(ok);
        if (t == 0) nvalidS = __popcll(vm);        // asc d2 -> popcount == prefix
    }
    __syncthreads();
    const int nvalid = nvalidS;

    // ======== phase 2: h1 = relu(x @ W1a + rel @ W1b + b1), 4n x 4c ========
    {
        const int c0 = (t & 15) * 4, n0 = (t >> 4) * 4;
        float acc[4][4];
        #pragma unroll
        for (int ni = 0; ni < 4; ++ni)
            #pragma unroll
            for (int ci = 0; ci < 4; ++ci) acc[ni][ci] = 0.0f;

        #pragma unroll
        for (int kb4 = 0; kb4 < 16; ++kb4) {
            float4 av[4], wv[4];
            #pragma unroll
            for (int ki = 0; ki < 4; ++ki)
                av[ki] = *(const float4*)&u0.p2.xsT[kb4 * 4 + ki][n0];
            #pragma unroll
            for (int ki = 0; ki < 4; ++ki)
                wv[ki] = *(const float4*)&u0.p2.W1s[kb4 * 4 + ki][c0];
            #pragma unroll
            for (int ki = 0; ki < 4; ++ki) {       // k = 4*kb4 + ki, ascending
                #pragma unroll
                for (int ni = 0; ni < 4; ++ni) {
                    const float a = (&av[ki].x)[ni];
                    acc[ni][0] = __fmaf_rn(a, wv[ki].x, acc[ni][0]);
                    acc[ni][1] = __fmaf_rn(a, wv[ki].y, acc[ni][1]);
                    acc[ni][2] = __fmaf_rn(a, wv[ki].z, acc[ni][2]);
                    acc[ni][3] = __fmaf_rn(a, wv[ki].w, acc[ni][3]);
                }
            }
        }
        // rel terms from global (bit-identical subtraction), per-n registers
        float rr[4][3];
        #pragma unroll
        for (int ni = 0; ni < 4; ++ni) {
            const int j = selj[n0 + ni];
            rr[ni][0] = pos[j * 3 + 0] - xi;
            rr[ni][1] = pos[j * 3 + 1] - yi;
            rr[ni][2] = pos[j * 3 + 2] - zi;
        }
        #pragma unroll
        for (int ci = 0; ci < 4; ++ci) {
            const int c = c0 + ci;
            const float w1b0 = W1[4096 + c], w1b1 = W1[4160 + c],
                        w1b2 = W1[4224 + c];
            const float bc = b1[c];
            float4 hv;
            #pragma unroll
            for (int ni = 0; ni < 4; ++ni) {
                const int n = n0 + ni;
                float a = acc[ni][ci];
                a = __fmaf_rn(rr[ni][0], w1b0, a);
                a = __fmaf_rn(rr[ni][1], w1b1, a);
                a = __fmaf_rn(rr[ni][2], w1b2, a);
                a = fmaxf(a + bc, 0.0f);
                (&hv.x)[ni] = (n < nvalid) ? a : 0.0f;
            }
            *(float4*)&h1T[c][n0] = hv;
        }
    }
    __syncthreads();

    // ======== stage W2 into LDS (overlays W1s/xsT, both dead) ==============
    {
        const float4* src = (const float4*)W2;
        float4*       dst = (float4*)&u0.p3.W2s[0][0];
        for (int v = t; v < 2048; v += 256) dst[v] = src[v];
    }
    __syncthreads();

    // ======== phase 3: h2 = relu(h1 @ W2 + b2); masked max over n ==========
    {
        const int c2b = (t & 15) * 8;
        const int nb  = (t >> 4) * 4;
        float acc[4][8];
        #pragma unroll
        for (int ni = 0; ni < 4; ++ni)
            #pragma unroll
            for (int k = 0; k < 8; ++k) acc[ni][k] = 0.0f;

        #pragma unroll 4
        for (int cc = 0; cc < 64; ++cc) {          // cc ascending: same chain
            const float4 hv = *(const float4*)&h1T[cc][nb];
            const float4 w0 = *(const float4*)&u0.p3.W2s[cc][c2b];
            const float4 w1 = *(const float4*)&u0.p3.W2s[cc][c2b + 4];
            const float wv[8] = {w0.x, w0.y, w0.z, w0.w, w1.x, w1.y, w1.z, w1.w};
            #pragma unroll
            for (int k = 0; k < 8; ++k) {
                acc[0][k] = __fmaf_rn(hv.x, wv[k], acc[0][k]);
                acc[1][k] = __fmaf_rn(hv.y, wv[k], acc[1][k]);
                acc[2][k] = __fmaf_rn(hv.z, wv[k], acc[2][k]);
                acc[3][k] = __fmaf_rn(hv.w, wv[k], acc[3][k]);
            }
        }
        float m8[8];
        #pragma unroll
        for (int k = 0; k < 8; ++k) {
            const float bb = b2[c2b + k];
            float mm = 0.0f;  // relu floor; valid set nonempty (self)
            #pragma unroll
            for (int ni = 0; ni < 4; ++ni)
                if (nb + ni < nvalid) mm = fmaxf(mm, acc[ni][k] + bb);
            m8[k] = mm;
        }
        #pragma unroll
        for (int k = 0; k < 8; ++k) {              // exact max over wave's n-groups
            float v = m8[k];
            v = fmaxf(v, __shfl_down(v, 32));
            v = fmaxf(v, __shfl_down(v, 16));
            m8[k] = v;
        }
        if ((t & 63) < 16) {
            #pragma unroll
            for (int k = 0; k < 8; ++k) pmw[w][c2b + k] = m8[k];
        }
    }
    __syncthreads();

    if (t < 128)
        u0.p3.aggS[t] = fmaxf(fmaxf(pmw[0][t], pmw[1][t]),
                              fmaxf(pmw[2][t], pmw[3][t]));
    __syncthreads();

    // ======== phase 4: out[i][t] = relu(aggS . Wg[:,t] + bg[t]) ============
    {
        float acc = 0.0f;
        #pragma unroll 8
        for (int k = 0; k < 128; ++k)
            acc = __fmaf_rn(u0.p3.aggS[k], Wg[k * 256 + t], acc);
        out[i * 256 + t] = fmaxf(acc + bg[t], 0.0f);
    }
}

// ---------------------------------------------------------------------------
extern "C" void kernel_launch(void* const* d_in, const int* in_sizes, int n_in,
                              void* d_out, int out_size, void* d_ws, size_t ws_size,
                              hipStream_t stream) {
    const float* x   = (const float*)d_in[0];
    const float* pos = (const float*)d_in[1];
    // d_in[2] = batch (all zeros) — unused
    const float* W1 = (const float*)d_in[3];
    const float* b1 = (const float*)d_in[4];
    const float* W2 = (const float*)d_in[5];
    const float* b2 = (const float*)d_in[6];
    const float* Wg = (const float*)d_in[7];
    const float* bg = (const float*)d_in[8];
    float* out = (float*)d_out;

    fused_all<<<N_PTS, 256, 0, stream>>>(x, pos, W1, b1, W2, b2, Wg, bg, out);
}

// Round 11
// 734.164 us; speedup vs baseline: 2.3023x; 2.3023x over previous
//
#include <hip/hip_runtime.h>

#define N_PTS 8192
#define R2F 0.015625f   // R*R, exactly representable

// Phase-disjoint LDS regions share one union (R8 layout):
//  s  : per-wave sorted top-64 lists (extraction -> merge)
//  p2 : W1s + xs               (gather -> phase 2)
//  p3 : W2s + aggS             (phase 3 -> phase 4)
union Big {
    struct { unsigned mb[4][64]; unsigned mj[4][64]; } s;   // 2 KB
    struct { float W1s[67][64]; float xs[64][64]; } p2;     // 32.75 KB
    struct { float W2s[64][128]; float aggS[128]; } p3;     // 32.5 KB
};

__global__ __launch_bounds__(256) void fused_all(const float* __restrict__ x,
                                                 const float* __restrict__ pos,
                                                 const float* __restrict__ W1,
                                                 const float* __restrict__ b1,
                                                 const float* __restrict__ W2,
                                                 const float* __restrict__ b2,
                                                 const float* __restrict__ Wg,
                                                 const float* __restrict__ bg,
                                                 float* __restrict__ out) {
    __shared__ Big   u0;
    __shared__ float h1[64][64];     // 16 KB
    __shared__ float pmw[4][128];    // 2 KB per-wave partial maxima
    __shared__ unsigned selb[64];
    __shared__ int   selj[64];
    __shared__ float relS[64][3];
    __shared__ int   nvalidS;

    const int t    = threadIdx.x;
    const int lane = t & 63;
    const int w    = t >> 6;         // wave id; owns quarter j in [2048w, 2048w+2048)
    const int qb   = w << 11;
    const int i    = blockIdx.x;

    const float xi = pos[i * 3 + 0], yi = pos[i * 3 + 1], zi = pos[i * 3 + 2];
    const float sqi = __fadd_rn(__fadd_rn(__fmul_rn(xi, xi), __fmul_rn(yi, yi)),
                                __fmul_rn(zi, zi));

    // ---- phase 1: d2 keys for this wave's quarter, register-resident ----
    unsigned kb[32];
    #pragma unroll
    for (int k = 0; k < 32; ++k) {
        const int j = qb + lane + (k << 6);
        const float xj = pos[j * 3 + 0], yj = pos[j * 3 + 1], zj = pos[j * 3 + 2];
        const float sqj = __fadd_rn(__fadd_rn(__fmul_rn(xj, xj), __fmul_rn(yj, yj)),
                                    __fmul_rn(zj, zj));
        const float dot = __fmaf_rn(zi, zj, __fmaf_rn(yi, yj, __fmul_rn(xi, xj)));
        const float d2  = __fsub_rn(__fadd_rn(sqi, sqj), __fmul_rn(2.0f, dot));
        unsigned b = __float_as_uint(d2);
        kb[k] = (b & 0x80000000u) ? ~b : (b | 0x80000000u);  // monotone total order
    }

    // pre-fill this wave's merge list with UNIQUE pads, ascending in lane:
    // (0xFFFFFFFF, 0xFFFFFF00 | (w<<6) | lane) — sorts after every real entry,
    // no rank collisions in the merge (the R9 bug), prefix gets overwritten.
    u0.s.mb[w][lane] = 0xFFFFFFFFu;
    u0.s.mj[w][lane] = 0xFFFFFF00u | (unsigned)((w << 6) | lane);

    // ---- per-wave pops (R8 all-lane rescan), early exit once min > R^2 ----
    unsigned removed = 0u;
    for (int s = 0; s < 64; ++s) {
        unsigned lb = 0xFFFFFFFFu;
        int      lj = 0x7FFFFFFF;
        #pragma unroll
        for (int k = 0; k < 32; ++k) {
            if (!(removed & (1u << k))) {
                const unsigned b = kb[k];
                if (b < lb) { lb = b; lj = qb + lane + (k << 6); }
            }
        }
        unsigned rb = lb;
        int      rj = lj;
        #pragma unroll
        for (int off = 32; off > 0; off >>= 1) {
            const unsigned ob = (unsigned)__shfl_down((int)rb, off);
            const int      oj = __shfl_down(rj, off);
            if (ob < rb || (ob == rb && oj < rj)) { rb = ob; rj = oj; }
        }
        const unsigned wb = (unsigned)__shfl((int)rb, 0);
        const int      wj = __shfl(rj, 0);
        const unsigned db = (wb & 0x80000000u) ? (wb ^ 0x80000000u) : ~wb;
        if (!(__uint_as_float(db) <= R2F)) break;   // wave-uniform; pops ascend,
                                                    // so all <=R^2 already popped
        if (lane == 0) { u0.s.mb[w][s] = wb; u0.s.mj[w][s] = (unsigned)wj; }
        if (lb == wb && lj == wj)                   // unique owner lane
            removed |= 1u << ((wj - qb - lane) >> 6);
    }
    __syncthreads();

    // ---- merge: exact global top-64 by (b, j) via parallel rank ----
    // all keys unique (reals by construction, pads by (w,lane)) -> bijective
    {
        const int p = lane;
        const unsigned be = u0.s.mb[w][p];
        const unsigned je = u0.s.mj[w][p];
        int rank = p;
        #pragma unroll
        for (int d = 1; d < 4; ++d) {
            const int wp = (w + d) & 3;
            int lo = 0;
            #pragma unroll
            for (int st = 32; st > 0; st >>= 1) {
                const int idx = lo + st - 1;
                const unsigned ob = u0.s.mb[wp][idx];
                const unsigned oj = u0.s.mj[wp][idx];
                if (ob < be || (ob == be && oj < je)) lo += st;
            }
            {
                const unsigned ob = u0.s.mb[wp][lo];
                const unsigned oj = u0.s.mj[wp][lo];
                if (ob < be || (ob == be && oj < je)) lo += 1;
            }
            rank += lo;
        }
        if (rank < 64) { selb[rank] = be; selj[rank] = (int)(je & 8191u); }
    }
    __syncthreads();

    // ---- stage W1 (overwrites mb/mj), gather rel + x rows, nvalid ballot ----
    {
        const float4* src = (const float4*)W1;
        float4*       dst = (float4*)&u0.p2.W1s[0][0];
        for (int v = t; v < 1072; v += 256) dst[v] = src[v];   // 67*64/4
    }
    if (t < 64) {
        const int j = selj[t];
        relS[t][0] = pos[j * 3 + 0] - xi;
        relS[t][1] = pos[j * 3 + 1] - yi;
        relS[t][2] = pos[j * 3 + 2] - zi;
    }
    for (int v = t; v < 1024; v += 256) {
        const int n = v >> 4, c4 = (v & 15) * 4;   // rows >= nvalid never used
        *(float4*)&u0.p2.xs[n][c4] = *(const float4*)&x[selj[n] * 64 + c4];
    }
    {
        bool ok = false;
        if (t < 64) {
            const unsigned b = selb[t];
            const unsigned db = (b & 0x80000000u) ? (b ^ 0x80000000u) : ~b;
            ok = (__uint_as_float(db) <= R2F);     // pads decode NaN -> false
        }
        const unsigned long long vm = __ballot(ok);
        if (t == 0) nvalidS = __popcll(vm);        // asc d2 -> popcount == prefix
    }
    __syncthreads();
    const int nvalid = nvalidS;

    // ---- phase 2: h1 = relu(xs @ W1a + rel @ W1b + b1), 4n x 4c tiles ----
    {
        const int c0 = (t & 15) * 4, n0 = (t >> 4) * 4;
        float acc[4][4];
        #pragma unroll
        for (int ni = 0; ni < 4; ++ni)
            #pragma unroll
            for (int ci = 0; ci < 4; ++ci) acc[ni][ci] = 0.0f;
        #pragma unroll
        for (int kb4 = 0; kb4 < 16; ++kb4) {
            float4 av[4], wv[4];
            #pragma unroll
            for (int ni = 0; ni < 4; ++ni)
                av[ni] = *(const float4*)&u0.p2.xs[n0 + ni][kb4 * 4];
            #pragma unroll
            for (int ki = 0; ki < 4; ++ki)
                wv[ki] = *(const float4*)&u0.p2.W1s[kb4 * 4 + ki][c0];
            #pragma unroll
            for (int ki = 0; ki < 4; ++ki) {       // k = 4*kb4 + ki, ascending
                #pragma unroll
                for (int ni = 0; ni < 4; ++ni) {
                    const float a = (&av[ni].x)[ki];
                    acc[ni][0] = __fmaf_rn(a, wv[ki].x, acc[ni][0]);
                    acc[ni][1] = __fmaf_rn(a, wv[ki].y, acc[ni][1]);
                    acc[ni][2] = __fmaf_rn(a, wv[ki].z, acc[ni][2]);
                    acc[ni][3] = __fmaf_rn(a, wv[ki].w, acc[ni][3]);
                }
            }
        }
        #pragma unroll
        for (int ni = 0; ni < 4; ++ni) {
            const int n = n0 + ni;
            const float r0 = relS[n][0], r1 = relS[n][1], r2 = relS[n][2];
            float4 hv;
            #pragma unroll
            for (int ci = 0; ci < 4; ++ci) {
                const int c = c0 + ci;
                float a = acc[ni][ci];
                a = __fmaf_rn(r0, u0.p2.W1s[64][c], a);
                a = __fmaf_rn(r1, u0.p2.W1s[65][c], a);
                a = __fmaf_rn(r2, u0.p2.W1s[66][c], a);
                a = fmaxf(a + b1[c], 0.0f);
                (&hv.x)[ci] = (n < nvalid) ? a : 0.0f;
            }
            *(float4*)&h1[n][c0] = hv;
        }
    }
    __syncthreads();

    // ---- stage W2 into LDS (overlays W1s/xs, both dead) ----
    {
        const float4* src = (const float4*)W2;
        float4*       dst = (float4*)&u0.p3.W2s[0][0];
        for (int v = t; v < 2048; v += 256) dst[v] = src[v];
    }
    __syncthreads();

    // ---- phase 3: h2 = relu(h1 @ W2 + b2); masked max over n ----
    {
        const int c2b = (t & 15) * 8;
        const int nb  = (t >> 4) * 4;
        float acc[4][8];
        #pragma unroll
        for (int ni = 0; ni < 4; ++ni)
            #pragma unroll
            for (int k = 0; k < 8; ++k) acc[ni][k] = 0.0f;

        #pragma unroll 4
        for (int ccb = 0; ccb < 16; ++ccb) {
            float4 av[4];
            #pragma unroll
            for (int ni = 0; ni < 4; ++ni)
                av[ni] = *(const float4*)&h1[nb + ni][ccb * 4];
            #pragma unroll
            for (int ci = 0; ci < 4; ++ci) {       // cc = 4*ccb + ci, ascending
                const int cc = ccb * 4 + ci;
                const float4 w0 = *(const float4*)&u0.p3.W2s[cc][c2b];
                const float4 w1 = *(const float4*)&u0.p3.W2s[cc][c2b + 4];
                const float wv[8] = {w0.x, w0.y, w0.z, w0.w, w1.x, w1.y, w1.z, w1.w};
                #pragma unroll
                for (int k = 0; k < 8; ++k) {
                    acc[0][k] = __fmaf_rn((&av[0].x)[ci], wv[k], acc[0][k]);
                    acc[1][k] = __fmaf_rn((&av[1].x)[ci], wv[k], acc[1][k]);
                    acc[2][k] = __fmaf_rn((&av[2].x)[ci], wv[k], acc[2][k]);
                    acc[3][k] = __fmaf_rn((&av[3].x)[ci], wv[k], acc[3][k]);
                }
            }
        }
        float m8[8];
        #pragma unroll
        for (int k = 0; k < 8; ++k) {
            const float bb = b2[c2b + k];
            float mm = 0.0f;  // relu floor; valid set nonempty (self)
            #pragma unroll
            for (int ni = 0; ni < 4; ++ni)
                if (nb + ni < nvalid) mm = fmaxf(mm, acc[ni][k] + bb);
            m8[k] = mm;
        }
        #pragma unroll
        for (int k = 0; k < 8; ++k) {              // exact max-reduce over n-groups
            float v = m8[k];
            v = fmaxf(v, __shfl_down(v, 32));
            v = fmaxf(v, __shfl_down(v, 16));
            m8[k] = v;
        }
        if ((t & 63) < 16) {
            #pragma unroll
            for (int k = 0; k < 8; ++k) pmw[w][c2b + k] = m8[k];
        }
    }
    __syncthreads();

    if (t < 128)
        u0.p3.aggS[t] = fmaxf(fmaxf(pmw[0][t], pmw[1][t]),
                              fmaxf(pmw[2][t], pmw[3][t]));
    __syncthreads();

    // ---- phase 4: out[i][t] = relu(aggS . Wg[:,t] + bg[t]) ----
    {
        float acc = 0.0f;
        #pragma unroll 8
        for (int k = 0; k < 128; ++k)
            acc = __fmaf_rn(u0.p3.aggS[k], Wg[k * 256 + t], acc);
        out[i * 256 + t] = fmaxf(acc + bg[t], 0.0f);
    }
}

// ---------------------------------------------------------------------------
extern "C" void kernel_launch(void* const* d_in, const int* in_sizes, int n_in,
                              void* d_out, int out_size, void* d_ws, size_t ws_size,
                              hipStream_t stream) {
    const float* x   = (const float*)d_in[0];
    const float* pos = (const float*)d_in[1];
    // d_in[2] = batch (all zeros) — unused
    const float* W1 = (const float*)d_in[3];
    const float* b1 = (const float*)d_in[4];
    const float* W2 = (const float*)d_in[5];
    const float* b2 = (const float*)d_in[6];
    const float* Wg = (const float*)d_in[7];
    const float* bg = (const float*)d_in[8];
    float* out = (float*)d_out;

    fused_all<<<N_PTS, 256, 0, stream>>>(x, pos, W1, b1, W2, b2, Wg, bg, out);
}

// Round 12
// 635.967 us; speedup vs baseline: 2.6578x; 1.1544x over previous
//
#include <hip/hip_runtime.h>

#define N_PTS 8192
#define R2F 0.015625f   // R*R, exactly representable

// Phase-disjoint LDS regions share one union:
//  s  : per-wave sorted top-64 lists (extraction -> merge)  [R11-verbatim]
//  p2 : W1s + xs (pad 68)       (gather -> phase 2)
//  p3 : W2s + aggS + pmw        (phase 3 -> phase 4)
union Big {
    struct { unsigned mb[4][64]; unsigned mj[4][64]; } s;               // 2 KB
    struct { float W1s[67][64]; float xs[64][68]; } p2;                 // 34560 B
    struct { float W2s[64][128]; float aggS[128]; float pmw[4][128]; } p3; // 35328 B
};

__global__ __launch_bounds__(256) void fused_all(const float* __restrict__ x,
                                                 const float* __restrict__ pos,
                                                 const float* __restrict__ W1,
                                                 const float* __restrict__ b1,
                                                 const float* __restrict__ W2,
                                                 const float* __restrict__ b2,
                                                 const float* __restrict__ Wg,
                                                 const float* __restrict__ bg,
                                                 float* __restrict__ out) {
    __shared__ Big   u0;             // ~35.3 KB
    __shared__ float h1[64][68];     // 17 KB, stride 68 == 4 (mod 32): conflict-free
    __shared__ unsigned selb[64];
    __shared__ int   selj[64];
    __shared__ int   nvalidS;

    const int t    = threadIdx.x;
    const int lane = t & 63;
    const int w    = t >> 6;         // wave id; owns quarter j in [2048w, 2048w+2048)
    const int qb   = w << 11;
    const int i    = blockIdx.x;

    const float xi = pos[i * 3 + 0], yi = pos[i * 3 + 1], zi = pos[i * 3 + 2];
    const float sqi = __fadd_rn(__fadd_rn(__fmul_rn(xi, xi), __fmul_rn(yi, yi)),
                                __fmul_rn(zi, zi));

    // ================ extraction: R11-VERBATIM (proven bit-exact) ==========
    unsigned kb[32];
    #pragma unroll
    for (int k = 0; k < 32; ++k) {
        const int j = qb + lane + (k << 6);
        const float xj = pos[j * 3 + 0], yj = pos[j * 3 + 1], zj = pos[j * 3 + 2];
        const float sqj = __fadd_rn(__fadd_rn(__fmul_rn(xj, xj), __fmul_rn(yj, yj)),
                                    __fmul_rn(zj, zj));
        const float dot = __fmaf_rn(zi, zj, __fmaf_rn(yi, yj, __fmul_rn(xi, xj)));
        const float d2  = __fsub_rn(__fadd_rn(sqi, sqj), __fmul_rn(2.0f, dot));
        unsigned b = __float_as_uint(d2);
        kb[k] = (b & 0x80000000u) ? ~b : (b | 0x80000000u);  // monotone total order
    }

    // unique ascending pads: no rank collisions in the merge (the R9 bug)
    u0.s.mb[w][lane] = 0xFFFFFFFFu;
    u0.s.mj[w][lane] = 0xFFFFFF00u | (unsigned)((w << 6) | lane);

    unsigned removed = 0u;
    for (int s = 0; s < 64; ++s) {
        unsigned lb = 0xFFFFFFFFu;
        int      lj = 0x7FFFFFFF;
        #pragma unroll
        for (int k = 0; k < 32; ++k) {
            if (!(removed & (1u << k))) {
                const unsigned b = kb[k];
                if (b < lb) { lb = b; lj = qb + lane + (k << 6); }
            }
        }
        unsigned rb = lb;
        int      rj = lj;
        #pragma unroll
        for (int off = 32; off > 0; off >>= 1) {
            const unsigned ob = (unsigned)__shfl_down((int)rb, off);
            const int      oj = __shfl_down(rj, off);
            if (ob < rb || (ob == rb && oj < rj)) { rb = ob; rj = oj; }
        }
        const unsigned wb = (unsigned)__shfl((int)rb, 0);
        const int      wj = __shfl(rj, 0);
        const unsigned db = (wb & 0x80000000u) ? (wb ^ 0x80000000u) : ~wb;
        if (!(__uint_as_float(db) <= R2F)) break;   // wave-uniform; pops ascend
        if (lane == 0) { u0.s.mb[w][s] = wb; u0.s.mj[w][s] = (unsigned)wj; }
        if (lb == wb && lj == wj)                   // unique owner lane
            removed |= 1u << ((wj - qb - lane) >> 6);
    }
    __syncthreads();

    {   // merge: exact global top-64 by (b, j) via parallel rank (bijective)
        const int p = lane;
        const unsigned be = u0.s.mb[w][p];
        const unsigned je = u0.s.mj[w][p];
        int rank = p;
        #pragma unroll
        for (int d = 1; d < 4; ++d) {
            const int wp = (w + d) & 3;
            int lo = 0;
            #pragma unroll
            for (int st = 32; st > 0; st >>= 1) {
                const int idx = lo + st - 1;
                const unsigned ob = u0.s.mb[wp][idx];
                const unsigned oj = u0.s.mj[wp][idx];
                if (ob < be || (ob == be && oj < je)) lo += st;
            }
            {
                const unsigned ob = u0.s.mb[wp][lo];
                const unsigned oj = u0.s.mj[wp][lo];
                if (ob < be || (ob == be && oj < je)) lo += 1;
            }
            rank += lo;
        }
        if (rank < 64) { selb[rank] = be; selj[rank] = (int)(je & 8191u); }
    }
    __syncthreads();

    // ======== stage W1 (overwrites mb/mj), gather x rows, nvalid ballot =====
    {
        const float4* src = (const float4*)W1;
        float4*       dst = (float4*)&u0.p2.W1s[0][0];
        for (int v = t; v < 1072; v += 256) dst[v] = src[v];   // 67*64/4
    }
    for (int v = t; v < 1024; v += 256) {
        const int n = v >> 4, c4 = (v & 15) * 4;   // rows >= nvalid never used
        *(float4*)&u0.p2.xs[n][c4] = *(const float4*)&x[selj[n] * 64 + c4];
    }
    {
        bool ok = false;
        if (t < 64) {
            const unsigned b = selb[t];
            const unsigned db = (b & 0x80000000u) ? (b ^ 0x80000000u) : ~b;
            ok = (__uint_as_float(db) <= R2F);     // pads decode NaN -> false
        }
        const unsigned long long vm = __ballot(ok);
        if (t == 0) nvalidS = __popcll(vm);        // asc d2 -> popcount == prefix
    }
    __syncthreads();
    const int nvalid = nvalidS;

    // ======== phase 2: h1 = relu(xs @ W1a + rel @ W1b + b1), 4n x 4c ========
    {
        const int c0 = (t & 15) * 4, n0 = (t >> 4) * 4;
        float acc[4][4];
        #pragma unroll
        for (int ni = 0; ni < 4; ++ni)
            #pragma unroll
            for (int ci = 0; ci < 4; ++ci) acc[ni][ci] = 0.0f;
        #pragma unroll
        for (int kb4 = 0; kb4 < 16; ++kb4) {
            float4 av[4], wv[4];
            #pragma unroll
            for (int ni = 0; ni < 4; ++ni)
                av[ni] = *(const float4*)&u0.p2.xs[n0 + ni][kb4 * 4];
            #pragma unroll
            for (int ki = 0; ki < 4; ++ki)
                wv[ki] = *(const float4*)&u0.p2.W1s[kb4 * 4 + ki][c0];
            #pragma unroll
            for (int ki = 0; ki < 4; ++ki) {       // k = 4*kb4 + ki, ascending
                #pragma unroll
                for (int ni = 0; ni < 4; ++ni) {
                    const float a = (&av[ni].x)[ki];
                    acc[ni][0] = __fmaf_rn(a, wv[ki].x, acc[ni][0]);
                    acc[ni][1] = __fmaf_rn(a, wv[ki].y, acc[ni][1]);
                    acc[ni][2] = __fmaf_rn(a, wv[ki].z, acc[ni][2]);
                    acc[ni][3] = __fmaf_rn(a, wv[ki].w, acc[ni][3]);
                }
            }
        }
        // rel from global pos (bit-identical subtraction; R10-proven)
        float rr[4][3];
        #pragma unroll
        for (int ni = 0; ni < 4; ++ni) {
            const int j = selj[n0 + ni];
            rr[ni][0] = pos[j * 3 + 0] - xi;
            rr[ni][1] = pos[j * 3 + 1] - yi;
            rr[ni][2] = pos[j * 3 + 2] - zi;
        }
        #pragma unroll
        for (int ni = 0; ni < 4; ++ni) {
            const int n = n0 + ni;
            float4 hv;
            #pragma unroll
            for (int ci = 0; ci < 4; ++ci) {
                const int c = c0 + ci;
                float a = acc[ni][ci];
                a = __fmaf_rn(rr[ni][0], u0.p2.W1s[64][c], a);
                a = __fmaf_rn(rr[ni][1], u0.p2.W1s[65][c], a);
                a = __fmaf_rn(rr[ni][2], u0.p2.W1s[66][c], a);
                a = fmaxf(a + b1[c], 0.0f);
                (&hv.x)[ci] = (n < nvalid) ? a : 0.0f;
            }
            *(float4*)&h1[n][c0] = hv;
        }
    }
    __syncthreads();

    // ======== stage W2 into LDS (overlays W1s/xs, both dead) ================
    {
        const float4* src = (const float4*)W2;
        float4*       dst = (float4*)&u0.p3.W2s[0][0];
        for (int v = t; v < 2048; v += 256) dst[v] = src[v];
    }
    __syncthreads();

    // ======== phase 3: h2 = relu(h1 @ W2 + b2); masked max over n ==========
    // thread owns channels [c4..c4+3] and [64+c4..64+c4+3]: contiguous b128
    // reads across the wave (2-way banks, free). Per-channel chain unchanged.
    {
        const int c4 = (t & 15) * 4;
        const int nb = (t >> 4) * 4;
        float acc[4][8];
        #pragma unroll
        for (int ni = 0; ni < 4; ++ni)
            #pragma unroll
            for (int k = 0; k < 8; ++k) acc[ni][k] = 0.0f;

        #pragma unroll 4
        for (int ccb = 0; ccb < 16; ++ccb) {
            float4 av[4];
            #pragma unroll
            for (int ni = 0; ni < 4; ++ni)
                av[ni] = *(const float4*)&h1[nb + ni][ccb * 4];
            #pragma unroll
            for (int ci = 0; ci < 4; ++ci) {       // cc = 4*ccb + ci, ascending
                const int cc = ccb * 4 + ci;
                const float4 w0 = *(const float4*)&u0.p3.W2s[cc][c4];
                const float4 w1 = *(const float4*)&u0.p3.W2s[cc][c4 + 64];
                const float wv[8] = {w0.x, w0.y, w0.z, w0.w, w1.x, w1.y, w1.z, w1.w};
                #pragma unroll
                for (int k = 0; k < 8; ++k) {
                    acc[0][k] = __fmaf_rn((&av[0].x)[ci], wv[k], acc[0][k]);
                    acc[1][k] = __fmaf_rn((&av[1].x)[ci], wv[k], acc[1][k]);
                    acc[2][k] = __fmaf_rn((&av[2].x)[ci], wv[k], acc[2][k]);
                    acc[3][k] = __fmaf_rn((&av[3].x)[ci], wv[k], acc[3][k]);
                }
            }
        }
        float m8[8];
        #pragma unroll
        for (int k = 0; k < 8; ++k) {
            const int ch = (k < 4) ? (c4 + k) : (64 + c4 + k - 4);
            const float bb = b2[ch];
            float mm = 0.0f;  // relu floor; valid set nonempty (self)
            #pragma unroll
            for (int ni = 0; ni < 4; ++ni)
                if (nb + ni < nvalid) mm = fmaxf(mm, acc[ni][k] + bb);
            m8[k] = mm;
        }
        #pragma unroll
        for (int k = 0; k < 8; ++k) {              // exact max-reduce over n-groups
            float v = m8[k];
            v = fmaxf(v, __shfl_down(v, 32));
            v = fmaxf(v, __shfl_down(v, 16));
            m8[k] = v;
        }
        if ((t & 63) < 16) {
            #pragma unroll
            for (int k = 0; k < 4; ++k) u0.p3.pmw[w][c4 + k]      = m8[k];
            #pragma unroll
            for (int k = 4; k < 8; ++k) u0.p3.pmw[w][64 + c4 + k - 4] = m8[k];
        }
    }
    __syncthreads();

    if (t < 128)
        u0.p3.aggS[t] = fmaxf(fmaxf(u0.p3.pmw[0][t], u0.p3.pmw[1][t]),
                              fmaxf(u0.p3.pmw[2][t], u0.p3.pmw[3][t]));
    __syncthreads();

    // ======== phase 4: out[i][t] = relu(aggS . Wg[:,t] + bg[t]) ============
    {
        float acc = 0.0f;
        #pragma unroll 8
        for (int k = 0; k < 128; ++k)
            acc = __fmaf_rn(u0.p3.aggS[k], Wg[k * 256 + t], acc);
        out[i * 256 + t] = fmaxf(acc + bg[t], 0.0f);
    }
}

// ---------------------------------------------------------------------------
extern "C" void kernel_launch(void* const* d_in, const int* in_sizes, int n_in,
                              void* d_out, int out_size, void* d_ws, size_t ws_size,
                              hipStream_t stream) {
    const float* x   = (const float*)d_in[0];
    const float* pos = (const float*)d_in[1];
    // d_in[2] = batch (all zeros) — unused
    const float* W1 = (const float*)d_in[3];
    const float* b1 = (const float*)d_in[4];
    const float* W2 = (const float*)d_in[5];
    const float* b2 = (const float*)d_in[6];
    const float* Wg = (const float*)d_in[7];
    const float* bg = (const float*)d_in[8];
    float* out = (float*)d_out;

    fused_all<<<N_PTS, 256, 0, stream>>>(x, pos, W1, b1, W2, b2, Wg, bg, out);
}

// Round 15
// 635.583 us; speedup vs baseline: 2.6594x; 1.0006x over previous
//
#include <hip/hip_runtime.h>

#define N_PTS 8192
#define R2F 0.015625f   // R*R, exactly representable

// Phase-disjoint LDS regions share one union (R12 layout):
//  s  : per-wave sorted top-64 lists (extraction -> merge)
//  p2 : W1s + xs (pad 68)       (gather -> phase 2)
//  p3 : W2s + aggS + pmw        (phase 3 -> phase 4)
union Big {
    struct { unsigned mb[4][64]; unsigned mj[4][64]; } s;               // 2 KB
    struct { float W1s[67][64]; float xs[64][68]; } p2;                 // 34560 B
    struct { float W2s[64][128]; float aggS[128]; float pmw[4][128]; } p3; // 35328 B
};

__global__ __launch_bounds__(256) void fused_all(const float* __restrict__ x,
                                                 const float* __restrict__ pos,
                                                 const float* __restrict__ W1,
                                                 const float* __restrict__ b1,
                                                 const float* __restrict__ W2,
                                                 const float* __restrict__ b2,
                                                 const float* __restrict__ Wg,
                                                 const float* __restrict__ bg,
                                                 float* __restrict__ out) {
    __shared__ Big   u0;             // ~35.3 KB
    __shared__ float h1[64][68];     // 17 KB, stride 68 == 4 (mod 32)
    __shared__ unsigned selb[64];
    __shared__ int   selj[64];
    __shared__ int   nvalidS;

    const int t    = threadIdx.x;
    const int lane = t & 63;
    const int w    = t >> 6;         // wave id; owns quarter j in [2048w, 2048w+2048)
    const int qb   = w << 11;
    const int i    = blockIdx.x;

    const float xi = pos[i * 3 + 0], yi = pos[i * 3 + 1], zi = pos[i * 3 + 2];
    const float sqi = __fadd_rn(__fadd_rn(__fmul_rn(xi, xi), __fmul_rn(yi, yi)),
                                __fmul_rn(zi, zi));

    // ---- phase 1: d2 keys for this wave's quarter, register-resident ----
    unsigned kb[32];
    #pragma unroll
    for (int k = 0; k < 32; ++k) {
        const int j = qb + lane + (k << 6);
        const float xj = pos[j * 3 + 0], yj = pos[j * 3 + 1], zj = pos[j * 3 + 2];
        const float sqj = __fadd_rn(__fadd_rn(__fmul_rn(xj, xj), __fmul_rn(yj, yj)),
                                    __fmul_rn(zj, zj));
        const float dot = __fmaf_rn(zi, zj, __fmaf_rn(yi, yj, __fmul_rn(xi, xj)));
        const float d2  = __fsub_rn(__fadd_rn(sqi, sqj), __fmul_rn(2.0f, dot));
        unsigned b = __float_as_uint(d2);
        kb[k] = (b & 0x80000000u) ? ~b : (b | 0x80000000u);  // monotone total order
    }

    // unique ascending pads: no rank collisions in the merge (the R9 bug)
    u0.s.mb[w][lane] = 0xFFFFFFFFu;
    u0.s.mj[w][lane] = 0xFFFFFF00u | (unsigned)((w << 6) | lane);

    // ---- per-wave pops with early exit (R12-proven semantics).
    // Change vs R12: persistent per-lane (lb, lj); only the pop's OWNER lane
    // rescans its 32 slots. Non-owner minima provably unchanged -> every
    // pop's reduce sees identical inputs to R12's all-lane rescan.
    unsigned removed = 0u;
    unsigned lb = 0xFFFFFFFFu;
    int      lj = 0x7FFFFFFF;
    #pragma unroll
    for (int k = 0; k < 32; ++k) {
        const unsigned b = kb[k];
        if (b < lb) { lb = b; lj = qb + lane + (k << 6); }
    }
    for (int s = 0; s < 64; ++s) {
        unsigned rb = lb;
        int      rj = lj;
        #pragma unroll
        for (int off = 32; off > 0; off >>= 1) {
            const unsigned ob = (unsigned)__shfl_down((int)rb, off);
            const int      oj = __shfl_down(rj, off);
            if (ob < rb || (ob == rb && oj < rj)) { rb = ob; rj = oj; }
        }
        const unsigned wb = (unsigned)__shfl((int)rb, 0);
        const int      wj = __shfl(rj, 0);
        const unsigned db = (wb & 0x80000000u) ? (wb ^ 0x80000000u) : ~wb;
        if (!(__uint_as_float(db) <= R2F)) break;   // wave-uniform; pops ascend
        if (lane == 0) { u0.s.mb[w][s] = wb; u0.s.mj[w][s] = (unsigned)wj; }
        if (lb == wb && lj == wj) {                 // unique owner lane
            removed |= 1u << ((wj - qb - lane) >> 6);
            lb = 0xFFFFFFFFu; lj = 0x7FFFFFFF;      // owner-only rescan
            #pragma unroll
            for (int k = 0; k < 32; ++k) {
                if (!(removed & (1u << k))) {
                    const unsigned b = kb[k];
                    if (b < lb) { lb = b; lj = qb + lane + (k << 6); }
                }
            }
        }
    }
    __syncthreads();

    {   // merge: exact global top-64 by (b, j) via parallel rank (bijective)
        const int p = lane;
        const unsigned be = u0.s.mb[w][p];
        const unsigned je = u0.s.mj[w][p];
        int rank = p;
        #pragma unroll
        for (int d = 1; d < 4; ++d) {
            const int wp = (w + d) & 3;
            int lo = 0;
            #pragma unroll
            for (int st = 32; st > 0; st >>= 1) {
                const int idx = lo + st - 1;
                const unsigned ob = u0.s.mb[wp][idx];
                const unsigned oj = u0.s.mj[wp][idx];
                if (ob < be || (ob == be && oj < je)) lo += st;
            }
            {
                const unsigned ob = u0.s.mb[wp][lo];
                const unsigned oj = u0.s.mj[wp][lo];
                if (ob < be || (ob == be && oj < je)) lo += 1;
            }
            rank += lo;
        }
        if (rank < 64) { selb[rank] = be; selj[rank] = (int)(je & 8191u); }
    }
    __syncthreads();

    // ======== stage W1 (overwrites mb/mj), gather x rows, nvalid ballot =====
    {
        const float4* src = (const float4*)W1;
        float4*       dst = (float4*)&u0.p2.W1s[0][0];
        for (int v = t; v < 1072; v += 256) dst[v] = src[v];   // 67*64/4
    }
    for (int v = t; v < 1024; v += 256) {
        const int n = v >> 4, c4 = (v & 15) * 4;   // rows >= nvalid never used
        *(float4*)&u0.p2.xs[n][c4] = *(const float4*)&x[selj[n] * 64 + c4];
    }
    {
        bool ok = false;
        if (t < 64) {
            const unsigned b = selb[t];
            const unsigned db = (b & 0x80000000u) ? (b ^ 0x80000000u) : ~b;
            ok = (__uint_as_float(db) <= R2F);     // pads decode NaN -> false
        }
        const unsigned long long vm = __ballot(ok);
        if (t == 0) nvalidS = __popcll(vm);        // asc d2 -> popcount == prefix
    }
    __syncthreads();
    const int nvalid = nvalidS;

    // ======== phase 2: h1 = relu(xs @ W1a + rel @ W1b + b1), 4n x 4c ========
    {
        const int c0 = (t & 15) * 4, n0 = (t >> 4) * 4;
        float acc[4][4];
        #pragma unroll
        for (int ni = 0; ni < 4; ++ni)
            #pragma unroll
            for (int ci = 0; ci < 4; ++ci) acc[ni][ci] = 0.0f;
        #pragma unroll
        for (int kb4 = 0; kb4 < 16; ++kb4) {
            float4 av[4], wv[4];
            #pragma unroll
            for (int ni = 0; ni < 4; ++ni)
                av[ni] = *(const float4*)&u0.p2.xs[n0 + ni][kb4 * 4];
            #pragma unroll
            for (int ki = 0; ki < 4; ++ki)
                wv[ki] = *(const float4*)&u0.p2.W1s[kb4 * 4 + ki][c0];
            #pragma unroll
            for (int ki = 0; ki < 4; ++ki) {       // k = 4*kb4 + ki, ascending
                #pragma unroll
                for (int ni = 0; ni < 4; ++ni) {
                    const float a = (&av[ni].x)[ki];
                    acc[ni][0] = __fmaf_rn(a, wv[ki].x, acc[ni][0]);
                    acc[ni][1] = __fmaf_rn(a, wv[ki].y, acc[ni][1]);
                    acc[ni][2] = __fmaf_rn(a, wv[ki].z, acc[ni][2]);
                    acc[ni][3] = __fmaf_rn(a, wv[ki].w, acc[ni][3]);
                }
            }
        }
        // rel from global pos (bit-identical subtraction; R10-proven)
        float rr[4][3];
        #pragma unroll
        for (int ni = 0; ni < 4; ++ni) {
            const int j = selj[n0 + ni];
            rr[ni][0] = pos[j * 3 + 0] - xi;
            rr[ni][1] = pos[j * 3 + 1] - yi;
            rr[ni][2] = pos[j * 3 + 2] - zi;
        }
        #pragma unroll
        for (int ni = 0; ni < 4; ++ni) {
            const int n = n0 + ni;
            float4 hv;
            #pragma unroll
            for (int ci = 0; ci < 4; ++ci) {
                const int c = c0 + ci;
                float a = acc[ni][ci];
                a = __fmaf_rn(rr[ni][0], u0.p2.W1s[64][c], a);
                a = __fmaf_rn(rr[ni][1], u0.p2.W1s[65][c], a);
                a = __fmaf_rn(rr[ni][2], u0.p2.W1s[66][c], a);
                a = fmaxf(a + b1[c], 0.0f);
                (&hv.x)[ci] = (n < nvalid) ? a : 0.0f;
            }
            *(float4*)&h1[n][c0] = hv;
        }
    }
    __syncthreads();

    // ======== stage W2 into LDS (overlays W1s/xs, both dead) ================
    {
        const float4* src = (const float4*)W2;
        float4*       dst = (float4*)&u0.p3.W2s[0][0];
        for (int v = t; v < 2048; v += 256) dst[v] = src[v];
    }
    __syncthreads();

    // ======== phase 3: h2 = relu(h1 @ W2 + b2); masked max over n ==========
    {
        const int c4 = (t & 15) * 4;
        const int nb = (t >> 4) * 4;
        float acc[4][8];
        #pragma unroll
        for (int ni = 0; ni < 4; ++ni)
            #pragma unroll
            for (int k = 0; k < 8; ++k) acc[ni][k] = 0.0f;

        #pragma unroll 4
        for (int ccb = 0; ccb < 16; ++ccb) {
            float4 av[4];
            #pragma unroll
            for (int ni = 0; ni < 4; ++ni)
                av[ni] = *(const float4*)&h1[nb + ni][ccb * 4];
            #pragma unroll
            for (int ci = 0; ci < 4; ++ci) {       // cc = 4*ccb + ci, ascending
                const int cc = ccb * 4 + ci;
                const float4 w0 = *(const float4*)&u0.p3.W2s[cc][c4];
                const float4 w1 = *(const float4*)&u0.p3.W2s[cc][c4 + 64];
                const float wv[8] = {w0.x, w0.y, w0.z, w0.w, w1.x, w1.y, w1.z, w1.w};
                #pragma unroll
                for (int k = 0; k < 8; ++k) {
                    acc[0][k] = __fmaf_rn((&av[0].x)[ci], wv[k], acc[0][k]);
                    acc[1][k] = __fmaf_rn((&av[1].x)[ci], wv[k], acc[1][k]);
                    acc[2][k] = __fmaf_rn((&av[2].x)[ci], wv[k], acc[2][k]);
                    acc[3][k] = __fmaf_rn((&av[3].x)[ci], wv[k], acc[3][k]);
                }
            }
        }
        float m8[8];
        #pragma unroll
        for (int k = 0; k < 8; ++k) {
            const int ch = (k < 4) ? (c4 + k) : (64 + c4 + k - 4);
            const float bb = b2[ch];
            float mm = 0.0f;  // relu floor; valid set nonempty (self)
            #pragma unroll
            for (int ni = 0; ni < 4; ++ni)
                if (nb + ni < nvalid) mm = fmaxf(mm, acc[ni][k] + bb);
            m8[k] = mm;
        }
        #pragma unroll
        for (int k = 0; k < 8; ++k) {              // exact max-reduce over n-groups
            float v = m8[k];
            v = fmaxf(v, __shfl_down(v, 32));
            v = fmaxf(v, __shfl_down(v, 16));
            m8[k] = v;
        }
        if ((t & 63) < 16) {
            #pragma unroll
            for (int k = 0; k < 4; ++k) u0.p3.pmw[w][c4 + k]          = m8[k];
            #pragma unroll
            for (int k = 4; k < 8; ++k) u0.p3.pmw[w][64 + c4 + k - 4] = m8[k];
        }
    }
    __syncthreads();

    if (t < 128)
        u0.p3.aggS[t] = fmaxf(fmaxf(u0.p3.pmw[0][t], u0.p3.pmw[1][t]),
                              fmaxf(u0.p3.pmw[2][t], u0.p3.pmw[3][t]));
    __syncthreads();

    // ======== phase 4: out[i][t] = relu(aggS . Wg[:,t] + bg[t]) ============
    {
        float acc = 0.0f;
        #pragma unroll 8
        for (int k = 0; k < 128; ++k)
            acc = __fmaf_rn(u0.p3.aggS[k], Wg[k * 256 + t], acc);
        out[i * 256 + t] = fmaxf(acc + bg[t], 0.0f);
    }
}

// ---------------------------------------------------------------------------
extern "C" void kernel_launch(void* const* d_in, const int* in_sizes, int n_in,
                              void* d_out, int out_size, void* d_ws, size_t ws_size,
                              hipStream_t stream) {
    const float* x   = (const float*)d_in[0];
    const float* pos = (const float*)d_in[1];
    // d_in[2] = batch (all zeros) — unused
    const float* W1 = (const float*)d_in[3];
    const float* b1 = (const float*)d_in[4];
    const float* W2 = (const float*)d_in[5];
    const float* b2 = (const float*)d_in[6];
    const float* Wg = (const float*)d_in[7];
    const float* bg = (const float*)d_in[8];
    float* out = (float*)d_out;

    fused_all<<<N_PTS, 256, 0, stream>>>(x, pos, W1, b1, W2, b2, Wg, bg, out);
}

// Round 16
// 503.388 us; speedup vs baseline: 3.3578x; 1.2626x over previous
//
#include <hip/hip_runtime.h>

#define N_PTS 8192
#define R2F 0.015625f   // R*R, exactly representable

// ---------------- g = x @ W1a (NO bias; R15 phase-2 chain verbatim) --------
__global__ __launch_bounds__(256) void k_g(const float* __restrict__ x,
                                           const float* __restrict__ W1,
                                           float* __restrict__ g) {
    __shared__ float xs[64][68];
    __shared__ float ws_[64][64];
    const int t = threadIdx.x;
    const int r0 = blockIdx.x * 64;
    for (int v = t; v < 1024; v += 256)
        ((float4*)&ws_[0][0])[v] = ((const float4*)W1)[v];   // W1 rows 0..63
    for (int v = t; v < 1024; v += 256) {
        const int n = v >> 4, c4 = (v & 15) * 4;
        *(float4*)&xs[n][c4] = *(const float4*)&x[(r0 + n) * 64 + c4];
    }
    __syncthreads();
    const int c0 = (t & 15) * 4, n0 = (t >> 4) * 4;
    float acc[4][4];
    #pragma unroll
    for (int ni = 0; ni < 4; ++ni)
        #pragma unroll
        for (int ci = 0; ci < 4; ++ci) acc[ni][ci] = 0.0f;
    #pragma unroll
    for (int kb4 = 0; kb4 < 16; ++kb4) {
        float4 av[4], wv[4];
        #pragma unroll
        for (int ni = 0; ni < 4; ++ni)
            av[ni] = *(const float4*)&xs[n0 + ni][kb4 * 4];
        #pragma unroll
        for (int ki = 0; ki < 4; ++ki)
            wv[ki] = *(const float4*)&ws_[kb4 * 4 + ki][c0];
        #pragma unroll
        for (int ki = 0; ki < 4; ++ki) {           // k = 4*kb4 + ki, ascending
            #pragma unroll
            for (int ni = 0; ni < 4; ++ni) {
                const float a = (&av[ni].x)[ki];
                acc[ni][0] = __fmaf_rn(a, wv[ki].x, acc[ni][0]);
                acc[ni][1] = __fmaf_rn(a, wv[ki].y, acc[ni][1]);
                acc[ni][2] = __fmaf_rn(a, wv[ki].z, acc[ni][2]);
                acc[ni][3] = __fmaf_rn(a, wv[ki].w, acc[ni][3]);
            }
        }
    }
    #pragma unroll
    for (int ni = 0; ni < 4; ++ni)
        *(float4*)&g[(r0 + n0 + ni) * 64 + c0] =
            make_float4(acc[ni][0], acc[ni][1], acc[ni][2], acc[ni][3]);
}

// ---------------- main fused kernel ----------------------------------------
// LDS: selection lists (dead after merge) union gathered-g rows.
union U0 {
    struct { unsigned mb[4][64]; unsigned mj[4][64]; } s;   // 2 KB
    float gs[64][68];                                       // 17408 B
};

__global__ __launch_bounds__(256) void fused_all(const float* __restrict__ g,
                                                 const float* __restrict__ pos,
                                                 const float* __restrict__ W1,
                                                 const float* __restrict__ b1,
                                                 const float* __restrict__ W2,
                                                 const float* __restrict__ b2,
                                                 const float* __restrict__ Wg,
                                                 const float* __restrict__ bg,
                                                 float* __restrict__ out) {
    __shared__ U0    u0;             // 17408 B
    __shared__ float h1[64][68];     // 17408 B, stride 68 == 4 (mod 32)
    __shared__ float pmw[4][128];    // 2 KB
    __shared__ float aggS[128];
    __shared__ unsigned selb[64];
    __shared__ int   selj[64];
    __shared__ int   nvalidS;

    const int t    = threadIdx.x;
    const int lane = t & 63;
    const int w    = t >> 6;         // wave id; owns quarter j in [2048w, 2048w+2048)
    const int qb   = w << 11;
    const int i    = blockIdx.x;

    const float xi = pos[i * 3 + 0], yi = pos[i * 3 + 1], zi = pos[i * 3 + 2];
    const float sqi = __fadd_rn(__fadd_rn(__fmul_rn(xi, xi), __fmul_rn(yi, yi)),
                                __fmul_rn(zi, zi));

    // ================ extraction: R15-VERBATIM (proven bit-exact) ==========
    unsigned kb[32];
    #pragma unroll
    for (int k = 0; k < 32; ++k) {
        const int j = qb + lane + (k << 6);
        const float xj = pos[j * 3 + 0], yj = pos[j * 3 + 1], zj = pos[j * 3 + 2];
        const float sqj = __fadd_rn(__fadd_rn(__fmul_rn(xj, xj), __fmul_rn(yj, yj)),
                                    __fmul_rn(zj, zj));
        const float dot = __fmaf_rn(zi, zj, __fmaf_rn(yi, yj, __fmul_rn(xi, xj)));
        const float d2  = __fsub_rn(__fadd_rn(sqi, sqj), __fmul_rn(2.0f, dot));
        unsigned b = __float_as_uint(d2);
        kb[k] = (b & 0x80000000u) ? ~b : (b | 0x80000000u);  // monotone total order
    }

    // unique ascending pads: no rank collisions in the merge (the R9 bug)
    u0.s.mb[w][lane] = 0xFFFFFFFFu;
    u0.s.mj[w][lane] = 0xFFFFFF00u | (unsigned)((w << 6) | lane);

    unsigned removed = 0u;
    unsigned lb = 0xFFFFFFFFu;
    int      lj = 0x7FFFFFFF;
    #pragma unroll
    for (int k = 0; k < 32; ++k) {
        const unsigned b = kb[k];
        if (b < lb) { lb = b; lj = qb + lane + (k << 6); }
    }
    for (int s = 0; s < 64; ++s) {
        unsigned rb = lb;
        int      rj = lj;
        #pragma unroll
        for (int off = 32; off > 0; off >>= 1) {
            const unsigned ob = (unsigned)__shfl_down((int)rb, off);
            const int      oj = __shfl_down(rj, off);
            if (ob < rb || (ob == rb && oj < rj)) { rb = ob; rj = oj; }
        }
        const unsigned wb = (unsigned)__shfl((int)rb, 0);
        const int      wj = __shfl(rj, 0);
        const unsigned db = (wb & 0x80000000u) ? (wb ^ 0x80000000u) : ~wb;
        if (!(__uint_as_float(db) <= R2F)) break;   // wave-uniform; pops ascend
        if (lane == 0) { u0.s.mb[w][s] = wb; u0.s.mj[w][s] = (unsigned)wj; }
        if (lb == wb && lj == wj) {                 // unique owner lane
            removed |= 1u << ((wj - qb - lane) >> 6);
            lb = 0xFFFFFFFFu; lj = 0x7FFFFFFF;      // owner-only rescan
            #pragma unroll
            for (int k = 0; k < 32; ++k) {
                if (!(removed & (1u << k))) {
                    const unsigned b = kb[k];
                    if (b < lb) { lb = b; lj = qb + lane + (k << 6); }
                }
            }
        }
    }
    __syncthreads();

    {   // merge: exact global top-64 by (b, j) via parallel rank (bijective)
        const int p = lane;
        const unsigned be = u0.s.mb[w][p];
        const unsigned je = u0.s.mj[w][p];
        int rank = p;
        #pragma unroll
        for (int d = 1; d < 4; ++d) {
            const int wp = (w + d) & 3;
            int lo = 0;
            #pragma unroll
            for (int st = 32; st > 0; st >>= 1) {
                const int idx = lo + st - 1;
                const unsigned ob = u0.s.mb[wp][idx];
                const unsigned oj = u0.s.mj[wp][idx];
                if (ob < be || (ob == be && oj < je)) lo += st;
            }
            {
                const unsigned ob = u0.s.mb[wp][lo];
                const unsigned oj = u0.s.mj[wp][lo];
                if (ob < be || (ob == be && oj < je)) lo += 1;
            }
            rank += lo;
        }
        if (rank < 64) { selb[rank] = be; selj[rank] = (int)(je & 8191u); }
    }
    __syncthreads();

    // ======== gather g rows (overwrites mb/mj), nvalid ballot ==============
    for (int v = t; v < 1024; v += 256) {
        const int n = v >> 4, c4 = (v & 15) * 4;   // rows >= nvalid never used
        *(float4*)&u0.gs[n][c4] = *(const float4*)&g[selj[n] * 64 + c4];
    }
    {
        bool ok = false;
        if (t < 64) {
            const unsigned b = selb[t];
            const unsigned db = (b & 0x80000000u) ? (b ^ 0x80000000u) : ~b;
            ok = (__uint_as_float(db) <= R2F);     // pads decode NaN -> false
        }
        const unsigned long long vm = __ballot(ok);
        if (t == 0) nvalidS = __popcll(vm);        // asc d2 -> popcount == prefix
    }
    __syncthreads();
    const int nvalid = nvalidS;

    // ======== phase 2: h1 = relu(g + rel @ W1b + b1)  (chain == R15) ========
    {
        const int c0 = (t & 15) * 4, n0 = (t >> 4) * 4;
        // rel from global pos (bit-identical subtraction; R10-proven)
        float rr[4][3];
        #pragma unroll
        for (int ni = 0; ni < 4; ++ni) {
            const int j = selj[n0 + ni];
            rr[ni][0] = pos[j * 3 + 0] - xi;
            rr[ni][1] = pos[j * 3 + 1] - yi;
            rr[ni][2] = pos[j * 3 + 2] - zi;
        }
        float w1b[3][4], bb[4];
        #pragma unroll
        for (int ci = 0; ci < 4; ++ci) {
            w1b[0][ci] = W1[4096 + c0 + ci];
            w1b[1][ci] = W1[4160 + c0 + ci];
            w1b[2][ci] = W1[4224 + c0 + ci];
            bb[ci]     = b1[c0 + ci];
        }
        #pragma unroll
        for (int ni = 0; ni < 4; ++ni) {
            const int n = n0 + ni;
            const float4 gv = *(const float4*)&u0.gs[n][c0];
            float4 hv;
            #pragma unroll
            for (int ci = 0; ci < 4; ++ci) {
                float a = (&gv.x)[ci];             // == R15 acc after k=0..63
                a = __fmaf_rn(rr[ni][0], w1b[0][ci], a);
                a = __fmaf_rn(rr[ni][1], w1b[1][ci], a);
                a = __fmaf_rn(rr[ni][2], w1b[2][ci], a);
                a = fmaxf(a + bb[ci], 0.0f);
                (&hv.x)[ci] = (n < nvalid) ? a : 0.0f;
            }
            *(float4*)&h1[n][c0] = hv;
        }
    }
    __syncthreads();

    // ======== phase 3: h2 = relu(h1 @ W2 + b2); masked max over n ==========
    // W2 read from global (value-identical to LDS staging; R8-proven path).
    {
        const int c4 = (t & 15) * 4;
        const int nb = (t >> 4) * 4;
        float acc[4][8];
        #pragma unroll
        for (int ni = 0; ni < 4; ++ni)
            #pragma unroll
            for (int k = 0; k < 8; ++k) acc[ni][k] = 0.0f;

        #pragma unroll 4
        for (int ccb = 0; ccb < 16; ++ccb) {
            float4 av[4];
            #pragma unroll
            for (int ni = 0; ni < 4; ++ni)
                av[ni] = *(const float4*)&h1[nb + ni][ccb * 4];
            #pragma unroll
            for (int ci = 0; ci < 4; ++ci) {       // cc = 4*ccb + ci, ascending
                const int cc = ccb * 4 + ci;
                const float4 w0 = *(const float4*)&W2[cc * 128 + c4];
                const float4 w1 = *(const float4*)&W2[cc * 128 + c4 + 64];
                const float wv[8] = {w0.x, w0.y, w0.z, w0.w, w1.x, w1.y, w1.z, w1.w};
                #pragma unroll
                for (int k = 0; k < 8; ++k) {
                    acc[0][k] = __fmaf_rn((&av[0].x)[ci], wv[k], acc[0][k]);
                    acc[1][k] = __fmaf_rn((&av[1].x)[ci], wv[k], acc[1][k]);
                    acc[2][k] = __fmaf_rn((&av[2].x)[ci], wv[k], acc[2][k]);
                    acc[3][k] = __fmaf_rn((&av[3].x)[ci], wv[k], acc[3][k]);
                }
            }
        }
        float m8[8];
        #pragma unroll
        for (int k = 0; k < 8; ++k) {
            const int ch = (k < 4) ? (c4 + k) : (64 + c4 + k - 4);
            const float bb = b2[ch];
            float mm = 0.0f;  // relu floor; valid set nonempty (self)
            #pragma unroll
            for (int ni = 0; ni < 4; ++ni)
                if (nb + ni < nvalid) mm = fmaxf(mm, acc[ni][k] + bb);
            m8[k] = mm;
        }
        #pragma unroll
        for (int k = 0; k < 8; ++k) {              // exact max-reduce over n-groups
            float v = m8[k];
            v = fmaxf(v, __shfl_down(v, 32));
            v = fmaxf(v, __shfl_down(v, 16));
            m8[k] = v;
        }
        if ((t & 63) < 16) {
            #pragma unroll
            for (int k = 0; k < 4; ++k) pmw[w][c4 + k]          = m8[k];
            #pragma unroll
            for (int k = 4; k < 8; ++k) pmw[w][64 + c4 + k - 4] = m8[k];
        }
    }
    __syncthreads();

    if (t < 128)
        aggS[t] = fmaxf(fmaxf(pmw[0][t], pmw[1][t]),
                        fmaxf(pmw[2][t], pmw[3][t]));
    __syncthreads();

    // ======== phase 4: out[i][t] = relu(aggS . Wg[:,t] + bg[t]) ============
    {
        float acc = 0.0f;
        #pragma unroll 8
        for (int k = 0; k < 128; ++k)
            acc = __fmaf_rn(aggS[k], Wg[k * 256 + t], acc);
        out[i * 256 + t] = fmaxf(acc + bg[t], 0.0f);
    }
}

// ---------------------------------------------------------------------------
extern "C" void kernel_launch(void* const* d_in, const int* in_sizes, int n_in,
                              void* d_out, int out_size, void* d_ws, size_t ws_size,
                              hipStream_t stream) {
    const float* x   = (const float*)d_in[0];
    const float* pos = (const float*)d_in[1];
    // d_in[2] = batch (all zeros) — unused
    const float* W1 = (const float*)d_in[3];
    const float* b1 = (const float*)d_in[4];
    const float* W2 = (const float*)d_in[5];
    const float* b2 = (const float*)d_in[6];
    const float* Wg = (const float*)d_in[7];
    const float* bg = (const float*)d_in[8];
    float* out = (float*)d_out;

    float* g = (float*)d_ws;   // 8192*64 floats = 2 MB, fully written by k_g

    k_g<<<N_PTS / 64, 256, 0, stream>>>(x, W1, g);
    fused_all<<<N_PTS, 256, 0, stream>>>(g, pos, W1, b1, W2, b2, Wg, bg, out);
}

// Round 17
// 420.072 us; speedup vs baseline: 4.0238x; 1.1983x over previous
//
#include <hip/hip_runtime.h>

#define N_PTS 8192
#define R2F 0.015625f   // R*R, exactly representable

// ---------------- g = x @ W1a (NO bias; R16 chain verbatim, 32-row tiles) ---
__global__ __launch_bounds__(256) void k_g(const float* __restrict__ x,
                                           const float* __restrict__ W1,
                                           float* __restrict__ g) {
    __shared__ float xs[32][68];
    __shared__ float ws_[64][64];
    const int t = threadIdx.x;
    const int r0 = blockIdx.x * 32;
    for (int v = t; v < 1024; v += 256)
        ((float4*)&ws_[0][0])[v] = ((const float4*)W1)[v];   // W1 rows 0..63
    for (int v = t; v < 512; v += 256) {
        const int n = v >> 4, c4 = (v & 15) * 4;
        *(float4*)&xs[n][c4] = *(const float4*)&x[(r0 + n) * 64 + c4];
    }
    __syncthreads();
    const int c0 = (t & 15) * 4, n0 = (t >> 4) * 2;
    float acc[2][4];
    #pragma unroll
    for (int ni = 0; ni < 2; ++ni)
        #pragma unroll
        for (int ci = 0; ci < 4; ++ci) acc[ni][ci] = 0.0f;
    #pragma unroll
    for (int kb4 = 0; kb4 < 16; ++kb4) {
        float4 av[2], wv[4];
        #pragma unroll
        for (int ni = 0; ni < 2; ++ni)
            av[ni] = *(const float4*)&xs[n0 + ni][kb4 * 4];
        #pragma unroll
        for (int ki = 0; ki < 4; ++ki)
            wv[ki] = *(const float4*)&ws_[kb4 * 4 + ki][c0];
        #pragma unroll
        for (int ki = 0; ki < 4; ++ki) {           // k = 4*kb4 + ki, ascending
            #pragma unroll
            for (int ni = 0; ni < 2; ++ni) {
                const float a = (&av[ni].x)[ki];
                acc[ni][0] = __fmaf_rn(a, wv[ki].x, acc[ni][0]);
                acc[ni][1] = __fmaf_rn(a, wv[ki].y, acc[ni][1]);
                acc[ni][2] = __fmaf_rn(a, wv[ki].z, acc[ni][2]);
                acc[ni][3] = __fmaf_rn(a, wv[ki].w, acc[ni][3]);
            }
        }
    }
    #pragma unroll
    for (int ni = 0; ni < 2; ++ni)
        *(float4*)&g[(r0 + n0 + ni) * 64 + c0] =
            make_float4(acc[ni][0], acc[ni][1], acc[ni][2], acc[ni][3]);
}

// ---------------- main fused kernel ----------------------------------------
// LDS: selection lists (dead after merge) union gathered-g rows; h1 is
// computed IN PLACE over gs (same (n,c) slot, same owning thread).
union U0 {
    struct { unsigned mb[4][64]; unsigned mj[4][64]; } s;   // 2 KB
    float gs[64][68];                                       // 17408 B
};

__global__ __launch_bounds__(256) void fused_all(const float* __restrict__ g,
                                                 const float* __restrict__ pos,
                                                 const float* __restrict__ W1,
                                                 const float* __restrict__ b1,
                                                 const float* __restrict__ W2,
                                                 const float* __restrict__ b2,
                                                 const float* __restrict__ Wg,
                                                 const float* __restrict__ bg,
                                                 float* __restrict__ out) {
    __shared__ U0    u0;             // 17408 B (total ~20.5 KB -> 7 blocks/CU)
    __shared__ float pmw[4][128];    // 2 KB
    __shared__ float aggS[128];
    __shared__ unsigned selb[64];
    __shared__ int   selj[64];
    __shared__ int   nvalidS;

    const int t    = threadIdx.x;
    const int lane = t & 63;
    const int w    = t >> 6;         // wave id; owns quarter j in [2048w, 2048w+2048)
    const int qb   = w << 11;
    const int i    = blockIdx.x;

    const float xi = pos[i * 3 + 0], yi = pos[i * 3 + 1], zi = pos[i * 3 + 2];
    const float sqi = __fadd_rn(__fadd_rn(__fmul_rn(xi, xi), __fmul_rn(yi, yi)),
                                __fmul_rn(zi, zi));

    // ---- phase 1: d2 keys; track per-lane two smallest (b, j) ----
    unsigned kb[32];
    unsigned m1b = 0xFFFFFFFFu, m2b = 0xFFFFFFFFu;
    int      m1j = 0x7FFFFFFF,  m2j = 0x7FFFFFFF;
    #pragma unroll
    for (int k = 0; k < 32; ++k) {
        const int j = qb + lane + (k << 6);
        const float xj = pos[j * 3 + 0], yj = pos[j * 3 + 1], zj = pos[j * 3 + 2];
        const float sqj = __fadd_rn(__fadd_rn(__fmul_rn(xj, xj), __fmul_rn(yj, yj)),
                                    __fmul_rn(zj, zj));
        const float dot = __fmaf_rn(zi, zj, __fmaf_rn(yi, yj, __fmul_rn(xi, xj)));
        const float d2  = __fsub_rn(__fadd_rn(sqi, sqj), __fmul_rn(2.0f, dot));
        unsigned b = __float_as_uint(d2);
        b = (b & 0x80000000u) ? ~b : (b | 0x80000000u);  // monotone total order
        kb[k] = b;
        // two-min update; j ascending, so on b-tie the incumbent (smaller j) wins
        if (b < m1b)      { m2b = m1b; m2j = m1j; m1b = b; m1j = j; }
        else if (b < m2b) { m2b = b;   m2j = j; }
    }

    // unique ascending pads: no rank collisions in the merge (the R9 bug)
    u0.s.mb[w][lane] = 0xFFFFFFFFu;
    u0.s.mj[w][lane] = 0xFFFFFF00u | (unsigned)((w << 6) | lane);

    // ---- pops with early exit; lazy lane-min: min1 -> min2 -> rescan ----
    // At every pop each lane's (lb, lj) == min over its unremoved keys
    // (level 0: min1; level 1: only min1 removed -> min2; level >= 2: rescan)
    // => reduce inputs identical to the R16-proven all-lane-rescan loop.
    unsigned removed = 0u;
    int      level = 0;
    unsigned lb = m1b;
    int      lj = m1j;
    for (int s = 0; s < 64; ++s) {
        unsigned rb = lb;
        int      rj = lj;
        #pragma unroll
        for (int off = 32; off > 0; off >>= 1) {
            const unsigned ob = (unsigned)__shfl_down((int)rb, off);
            const int      oj = __shfl_down(rj, off);
            if (ob < rb || (ob == rb && oj < rj)) { rb = ob; rj = oj; }
        }
        const unsigned wb = (unsigned)__shfl((int)rb, 0);
        const int      wj = __shfl(rj, 0);
        const unsigned db = (wb & 0x80000000u) ? (wb ^ 0x80000000u) : ~wb;
        if (!(__uint_as_float(db) <= R2F)) break;   // wave-uniform; pops ascend
        if (lane == 0) { u0.s.mb[w][s] = wb; u0.s.mj[w][s] = (unsigned)wj; }
        if (lb == wb && lj == wj) {                 // unique owner lane
            removed |= 1u << ((wj - qb - lane) >> 6);
            ++level;
            if (level == 1) { lb = m2b; lj = m2j; }
            else {                                  // rare (~3% of lanes)
                lb = 0xFFFFFFFFu; lj = 0x7FFFFFFF;
                #pragma unroll
                for (int k = 0; k < 32; ++k) {
                    if (!(removed & (1u << k))) {
                        const unsigned b = kb[k];
                        if (b < lb) { lb = b; lj = qb + lane + (k << 6); }
                    }
                }
            }
        }
    }
    __syncthreads();

    {   // merge: exact global top-64 by (b, j) via parallel rank (bijective)
        const int p = lane;
        const unsigned be = u0.s.mb[w][p];
        const unsigned je = u0.s.mj[w][p];
        int rank = p;
        #pragma unroll
        for (int d = 1; d < 4; ++d) {
            const int wp = (w + d) & 3;
            int lo = 0;
            #pragma unroll
            for (int st = 32; st > 0; st >>= 1) {
                const int idx = lo + st - 1;
                const unsigned ob = u0.s.mb[wp][idx];
                const unsigned oj = u0.s.mj[wp][idx];
                if (ob < be || (ob == be && oj < je)) lo += st;
            }
            {
                const unsigned ob = u0.s.mb[wp][lo];
                const unsigned oj = u0.s.mj[wp][lo];
                if (ob < be || (ob == be && oj < je)) lo += 1;
            }
            rank += lo;
        }
        if (rank < 64) { selb[rank] = be; selj[rank] = (int)(je & 8191u); }
    }
    __syncthreads();

    // ======== gather g rows (overwrites mb/mj), nvalid ballot ==============
    for (int v = t; v < 1024; v += 256) {
        const int n = v >> 4, c4 = (v & 15) * 4;   // rows >= nvalid never used
        *(float4*)&u0.gs[n][c4] = *(const float4*)&g[selj[n] * 64 + c4];
    }
    {
        bool ok = false;
        if (t < 64) {
            const unsigned b = selb[t];
            const unsigned db = (b & 0x80000000u) ? (b ^ 0x80000000u) : ~b;
            ok = (__uint_as_float(db) <= R2F);     // pads decode NaN -> false
        }
        const unsigned long long vm = __ballot(ok);
        if (t == 0) nvalidS = __popcll(vm);        // asc d2 -> popcount == prefix
    }
    __syncthreads();
    const int nvalid = nvalidS;

    // ======== phase 2: h1 = relu(g + rel @ W1b + b1), IN PLACE over gs ======
    // Each (n, c0..c0+3) slot is read and written by its owning thread only.
    {
        const int c0 = (t & 15) * 4, n0 = (t >> 4) * 4;
        float rr[4][3];
        #pragma unroll
        for (int ni = 0; ni < 4; ++ni) {
            const int j = selj[n0 + ni];
            rr[ni][0] = pos[j * 3 + 0] - xi;
            rr[ni][1] = pos[j * 3 + 1] - yi;
            rr[ni][2] = pos[j * 3 + 2] - zi;
        }
        float w1b[3][4], bb[4];
        #pragma unroll
        for (int ci = 0; ci < 4; ++ci) {
            w1b[0][ci] = W1[4096 + c0 + ci];
            w1b[1][ci] = W1[4160 + c0 + ci];
            w1b[2][ci] = W1[4224 + c0 + ci];
            bb[ci]     = b1[c0 + ci];
        }
        #pragma unroll
        for (int ni = 0; ni < 4; ++ni) {
            const int n = n0 + ni;
            const float4 gv = *(const float4*)&u0.gs[n][c0];
            float4 hv;
            #pragma unroll
            for (int ci = 0; ci < 4; ++ci) {
                float a = (&gv.x)[ci];             // == full ascending-k sum
                a = __fmaf_rn(rr[ni][0], w1b[0][ci], a);
                a = __fmaf_rn(rr[ni][1], w1b[1][ci], a);
                a = __fmaf_rn(rr[ni][2], w1b[2][ci], a);
                a = fmaxf(a + bb[ci], 0.0f);
                (&hv.x)[ci] = (n < nvalid) ? a : 0.0f;
            }
            *(float4*)&u0.gs[n][c0] = hv;          // in-place h1
        }
    }
    __syncthreads();

    // ======== phase 3: h2 = relu(h1 @ W2 + b2); masked max over n ==========
    // W2 from global (R16-proven path); h1 aliases u0.gs.
    {
        const float (*h1)[68] = u0.gs;
        const int c4 = (t & 15) * 4;
        const int nb = (t >> 4) * 4;
        float acc[4][8];
        #pragma unroll
        for (int ni = 0; ni < 4; ++ni)
            #pragma unroll
            for (int k = 0; k < 8; ++k) acc[ni][k] = 0.0f;

        #pragma unroll 4
        for (int ccb = 0; ccb < 16; ++ccb) {
            float4 av[4];
            #pragma unroll
            for (int ni = 0; ni < 4; ++ni)
                av[ni] = *(const float4*)&h1[nb + ni][ccb * 4];
            #pragma unroll
            for (int ci = 0; ci < 4; ++ci) {       // cc = 4*ccb + ci, ascending
                const int cc = ccb * 4 + ci;
                const float4 w0 = *(const float4*)&W2[cc * 128 + c4];
                const float4 w1 = *(const float4*)&W2[cc * 128 + c4 + 64];
                const float wv[8] = {w0.x, w0.y, w0.z, w0.w, w1.x, w1.y, w1.z, w1.w};
                #pragma unroll
                for (int k = 0; k < 8; ++k) {
                    acc[0][k] = __fmaf_rn((&av[0].x)[ci], wv[k], acc[0][k]);
                    acc[1][k] = __fmaf_rn((&av[1].x)[ci], wv[k], acc[1][k]);
                    acc[2][k] = __fmaf_rn((&av[2].x)[ci], wv[k], acc[2][k]);
                    acc[3][k] = __fmaf_rn((&av[3].x)[ci], wv[k], acc[3][k]);
                }
            }
        }
        float m8[8];
        #pragma unroll
        for (int k = 0; k < 8; ++k) {
            const int ch = (k < 4) ? (c4 + k) : (64 + c4 + k - 4);
            const float bb = b2[ch];
            float mm = 0.0f;  // relu floor; valid set nonempty (self)
            #pragma unroll
            for (int ni = 0; ni < 4; ++ni)
                if (nb + ni < nvalid) mm = fmaxf(mm, acc[ni][k] + bb);
            m8[k] = mm;
        }
        #pragma unroll
        for (int k = 0; k < 8; ++k) {              // exact max-reduce over n-groups
            float v = m8[k];
            v = fmaxf(v, __shfl_down(v, 32));
            v = fmaxf(v, __shfl_down(v, 16));
            m8[k] = v;
        }
        if ((t & 63) < 16) {
            #pragma unroll
            for (int k = 0; k < 4; ++k) pmw[w][c4 + k]          = m8[k];
            #pragma unroll
            for (int k = 4; k < 8; ++k) pmw[w][64 + c4 + k - 4] = m8[k];
        }
    }
    __syncthreads();

    if (t < 128)
        aggS[t] = fmaxf(fmaxf(pmw[0][t], pmw[1][t]),
                        fmaxf(pmw[2][t], pmw[3][t]));
    __syncthreads();

    // ======== phase 4: out[i][t] = relu(aggS . Wg[:,t] + bg[t]) ============
    {
        float acc = 0.0f;
        #pragma unroll 8
        for (int k = 0; k < 128; ++k)
            acc = __fmaf_rn(aggS[k], Wg[k * 256 + t], acc);
        out[i * 256 + t] = fmaxf(acc + bg[t], 0.0f);
    }
}

// ---------------------------------------------------------------------------
extern "C" void kernel_launch(void* const* d_in, const int* in_sizes, int n_in,
                              void* d_out, int out_size, void* d_ws, size_t ws_size,
                              hipStream_t stream) {
    const float* x   = (const float*)d_in[0];
    const float* pos = (const float*)d_in[1];
    // d_in[2] = batch (all zeros) — unused
    const float* W1 = (const float*)d_in[3];
    const float* b1 = (const float*)d_in[4];
    const float* W2 = (const float*)d_in[5];
    const float* b2 = (const float*)d_in[6];
    const float* Wg = (const float*)d_in[7];
    const float* bg = (const float*)d_in[8];
    float* out = (float*)d_out;

    float* g = (float*)d_ws;   // 8192*64 floats = 2 MB, fully written by k_g

    k_g<<<N_PTS / 32, 256, 0, stream>>>(x, W1, g);
    fused_all<<<N_PTS, 256, 0, stream>>>(g, pos, W1, b1, W2, b2, Wg, bg, out);
}